// Round 9
// baseline (785.409 us; speedup 1.0000x reference)
//
#include <hip/hip_runtime.h>
#include <hip/hip_fp16.h>

#define T_STEPS 336
#define NWG 32            // participating workgroups (one XCD's worth)
#define LAUNCH_WGS 256    // over-launch so some XCD gets >= NWG WGs (pigeonhole)

typedef unsigned long long u64;

// Device-global scratch; ALL sync state re-initialized by prep every call.
__device__ float g_h[337 * 512];      // h_1..h_336 (head reads t>=81)
__device__ float g_blw[256 * 512];    // sampled BayesianLinear weight
__device__ float g_blb[256];          // sampled BayesianLinear bias
__device__ u64   g_hh[2][512];        // parity buffers: (tag<<32)|h_bits
__device__ int   g_tick[8];           // per-XCD ticket counters (election)
__device__ int   g_winner;            // -1 until an XCD collects NWG WGs

__device__ __forceinline__ float softplus_f(float x) {
  return (x > 20.f) ? x : log1pf(__expf(x));
}
__device__ __forceinline__ float sigmoid_f(float x) {
  return 1.f / (1.f + __expf(-x));
}
__device__ __forceinline__ float tanh_f(float x) {
  x = fminf(fmaxf(x, -15.f), 15.f);
  float e = __expf(-2.f * x);
  return (1.f - e) / (1.f + e);
}

// Fast path: sc0 = L1-bypass, XCD-L2-served (intra-XCD coherent).
__device__ __forceinline__ u64 load_sc0(const u64* p) {
  u64 v;
  asm volatile("global_load_dwordx2 %0, %1, off sc0\n\ts_waitcnt vmcnt(0)"
               : "=v"(v) : "v"(p) : "memory");
  return v;
}
__device__ __forceinline__ void store_sc0(u64* p, u64 v) {
  asm volatile("global_store_dwordx2 %0, %1, off sc0" :: "v"(p), "v"(v) : "memory");
}

// ---------------- prep: BLW/BLb sampling + sync-state init ----------------
__global__ __launch_bounds__(256) void prep_kernel(
    const float* __restrict__ blw_mu, const float* __restrict__ blw_rho, const float* __restrict__ eps_blw,
    const float* __restrict__ blb_mu, const float* __restrict__ blb_rho, const float* __restrict__ eps_blb)
{
  const int bid = blockIdx.x, tid = threadIdx.x;
  if (bid < 512) {
    const int e = bid * 256 + tid;    // < 131072
    g_blw[e] = blw_mu[e] + softplus_f(blw_rho[e]) * eps_blw[e];
  } else {
    g_blb[tid] = blb_mu[tid] + softplus_f(blb_rho[tid]) * eps_blb[tid];
    // tag0|h0=0 both parities (parity-1 tag0 != 1 -> no false match).
    u64* p = &g_hh[0][0];
    #pragma unroll
    for (int q = 0; q < 4; ++q)
      __hip_atomic_store(p + q * 256 + tid, 0ULL, __ATOMIC_RELAXED,
                         __HIP_MEMORY_SCOPE_AGENT);
    if (tid < 8)
      __hip_atomic_store(&g_tick[tid], 0, __ATOMIC_RELAXED, __HIP_MEMORY_SCOPE_AGENT);
    if (tid == 8)
      __hip_atomic_store(&g_winner, -1, __ATOMIC_RELAXED, __HIP_MEMORY_SCOPE_AGENT);
  }
}

// ---------------- persistent LSTM recurrence (same-XCD cluster, safe) ----------------
// 256 WGs launched; 32 on one XCD win the election, the rest exit.
// Winner role r owns h-indices [16r,16r+16). Thread (seg=tid>>6, cl=tid&63):
// col=(cl>>4)*512+16r+(cl&15), rows [64seg,64seg+64), 64 Whh weights in regs.
// h exchange: dual-publish (sc0 -> local L2 fast path; agent/IC -> proven
// fallback), dual-poll (sc0 spin + IC probe every 4th iter + hard cap).
// hs copy in fp16 halves the ds_read_b128 count (round-7 bottleneck).
__global__ __launch_bounds__(512) void lstm_kernel(
    const float* __restrict__ x, const float* __restrict__ drop_x,
    const float* __restrict__ wih_mu, const float* __restrict__ wih_rho, const float* __restrict__ eps_wih,
    const float* __restrict__ b_mu, const float* __restrict__ b_rho, const float* __restrict__ eps_b,
    const float* __restrict__ whh_mu, const float* __restrict__ whh_rho, const float* __restrict__ eps_whh)
{
  const int tid = threadIdx.x;      // 0..511

  // ---- same-XCD election (terminates: 256 WGs / 8 XCDs -> some XCD hits NWG) ----
  __shared__ int s_role;
  if (tid == 0) {
    const int xcd = __builtin_amdgcn_s_getreg(6164) & 7;   // hwreg(XCC_ID,0,4)
    const int ticket = __hip_atomic_fetch_add(&g_tick[xcd], 1,
                          __ATOMIC_RELAXED, __HIP_MEMORY_SCOPE_AGENT);
    int role = -1;
    if (ticket < NWG) {
      if (ticket == NWG - 1) {
        int exp = -1;
        __hip_atomic_compare_exchange_strong(&g_winner, &exp, xcd,
            __ATOMIC_RELAXED, __ATOMIC_RELAXED, __HIP_MEMORY_SCOPE_AGENT);
      }
      int wv;
      do {
        wv = __hip_atomic_load(&g_winner, __ATOMIC_RELAXED, __HIP_MEMORY_SCOPE_AGENT);
      } while (wv == -1);
      if (wv == xcd) role = ticket;
    }
    s_role = role;
  }
  __syncthreads();
  const int r = s_role;
  if (r < 0) return;                // whole WG exits together

  const int cl = tid & 63;
  const int seg = tid >> 6;         // 0..7
  const int gate = cl >> 4, kl = cl & 15;
  const int col = gate * 512 + r * 16 + kl;
  const int row0 = seg * 64;

  __shared__ float  xd[336 * 16];   // x*drop_x for batch 255
  __shared__ __half hs16[512];      // fp16 h copy (matvec input only)
  __shared__ float  part[2][8][64]; // parity-double-buffered partials

  for (int e = tid; e < 5376; e += 512) {
    const int src = 255 * 5376 + e;   // batch-255 slice is contiguous
    xd[e] = x[src] * drop_x[src];
  }

  // 64 sampled Whh weights in registers (FULL unroll or w[] demotes to scratch).
  float w[64];
  #pragma unroll
  for (int j = 0; j < 64; ++j) {
    const int idx = (row0 + j) * 2048 + col;
    w[j] = whh_mu[idx] + softplus_f(whh_rho[idx]) * eps_whh[idx];
  }

  // Wave 0: Wih column + bias for on-the-fly xg.
  float wih[16];
  float bias = 0.f;
  if (tid < 64) {
    bias = b_mu[col] + softplus_f(b_rho[col]) * eps_b[col];
    #pragma unroll
    for (int i = 0; i < 16; ++i) {
      const int idx = i * 2048 + col;
      wih[i] = wih_mu[idx] + softplus_f(wih_rho[idx]) * eps_wih[idx];
    }
  }
  __syncthreads();                  // xd staged

  auto xg_at = [&](int t) -> float {
    const float4* xr = (const float4*)(xd + t * 16);
    float4 x0 = xr[0], x1 = xr[1], x2 = xr[2], x3 = xr[3];
    float s0 = fmaf(x0.x, wih[0], bias);
    s0 = fmaf(x0.y, wih[1], s0); s0 = fmaf(x0.z, wih[2], s0); s0 = fmaf(x0.w, wih[3], s0);
    float s1 = x1.x * wih[4];
    s1 = fmaf(x1.y, wih[5], s1); s1 = fmaf(x1.z, wih[6], s1); s1 = fmaf(x1.w, wih[7], s1);
    float s2 = x2.x * wih[8];
    s2 = fmaf(x2.y, wih[9], s2); s2 = fmaf(x2.z, wih[10], s2); s2 = fmaf(x2.w, wih[11], s2);
    float s3 = x3.x * wih[12];
    s3 = fmaf(x3.y, wih[13], s3); s3 = fmaf(x3.z, wih[14], s3); s3 = fmaf(x3.w, wih[15], s3);
    return (s0 + s1) + (s2 + s3);
  };

  float c = 0.f;
  float xgv = (tid < 64) ? xg_at(0) : 0.f;

  for (int t = 0; t < T_STEPS; ++t) {
    const int p = t & 1;

    // Dual-poll my slot: sc0 fast spin + IC probe (proven transport) + cap.
    {
      u64* slot = &g_hh[p][tid];
      u64 v;
      for (int it = 0; ; ++it) {
        v = load_sc0(slot);
        if ((unsigned)(v >> 32) == (unsigned)t) break;
        if ((it & 3) == 3) {
          v = __hip_atomic_load(slot, __ATOMIC_RELAXED, __HIP_MEMORY_SCOPE_AGENT);
          if ((unsigned)(v >> 32) == (unsigned)t) break;
          if (it > (1 << 18)) break;   // anti-hang insurance
        }
      }
      hs16[tid] = __float2half(__uint_as_float((unsigned)v));
    }
    // No barrier: wave seg's dot reads hs16[row0..row0+64) = its own lanes' data.

    float a0 = 0.f, a1 = 0.f, a2 = 0.f, a3 = 0.f;
    const float4* hv = (const float4*)(hs16 + row0);   // 8 halves per float4
    #pragma unroll
    for (int jj = 0; jj < 8; ++jj) {
      float4 q = hv[jj];
      const __half2* hp = (const __half2*)&q;
      float2 f0 = __half22float2(hp[0]);
      float2 f1 = __half22float2(hp[1]);
      float2 f2 = __half22float2(hp[2]);
      float2 f3 = __half22float2(hp[3]);
      a0 = fmaf(f0.x, w[8 * jj],     a0);
      a1 = fmaf(f0.y, w[8 * jj + 1], a1);
      a2 = fmaf(f1.x, w[8 * jj + 2], a2);
      a3 = fmaf(f1.y, w[8 * jj + 3], a3);
      a0 = fmaf(f2.x, w[8 * jj + 4], a0);
      a1 = fmaf(f2.y, w[8 * jj + 5], a1);
      a2 = fmaf(f3.x, w[8 * jj + 6], a2);
      a3 = fmaf(f3.y, w[8 * jj + 7], a3);
    }
    part[p][seg][cl] = (a0 + a1) + (a2 + a3);
    __syncthreads();   // single rendezvous per step (skew-safe via parity bufs)

    if (tid < 64) {
      float g = xgv
              + ((part[p][0][tid] + part[p][1][tid]) + (part[p][2][tid] + part[p][3][tid]))
              + ((part[p][4][tid] + part[p][5][tid]) + (part[p][6][tid] + part[p][7][tid]));
      float vi = __shfl(g, kl);
      float vf = __shfl(g, kl + 16);
      float vg = __shfl(g, kl + 32);
      float vo = __shfl(g, kl + 48);
      if (tid < 16) {
        float ig = sigmoid_f(vi);
        float fg = sigmoid_f(vf);
        float gg = tanh_f(vg);
        float og = sigmoid_f(vo);
        c = fg * c + ig * gg;
        float h = og * tanh_f(c);
        const int idx = r * 16 + tid;
        u64 pv = (((u64)(unsigned)(t + 1)) << 32) | (u64)__float_as_uint(h);
        store_sc0(&g_hh[(t + 1) & 1][idx], pv);            // fast path (local L2)
        __hip_atomic_store(&g_hh[(t + 1) & 1][idx], pv,    // fallback path (IC)
                           __ATOMIC_RELAXED, __HIP_MEMORY_SCOPE_AGENT);
        g_h[(t + 1) * 512 + idx] = h;                      // for head
      }
      if (t + 1 < T_STEPS) xgv = xg_at(t + 1);             // off critical path
    }
  }
}

// ---------------- head ----------------
// block j: last[j] = g_h[81+j]  (reshape(T,B,H)[-1] => h_{t=80+j} of batch 255)
__global__ __launch_bounds__(256) void head_kernel(
    const float* __restrict__ drop_h, const float* __restrict__ drop_l,
    const float* __restrict__ lin_w, float* __restrict__ out)
{
  const int j = blockIdx.x, tid = threadIdx.x;
  __shared__ float hd[512];
  __shared__ float y[256];

  for (int k = tid; k < 512; k += 256)
    hd[k] = g_h[(81 + j) * 512 + k] * drop_h[j * 512 + k];
  __syncthreads();

  {
    const int l = tid;
    float acc = g_blb[l];
    const float* wrow = g_blw + l * 512;
    #pragma unroll 8
    for (int k = 0; k < 512; ++k) acc = fmaf(hd[k], wrow[k], acc);
    acc = fmaxf(acc, 0.f);
    y[l] = acc * drop_l[j * 256 + l];
  }
  __syncthreads();

  if (tid < 10) {
    float acc = 0.f;
    const float* lrow = lin_w + tid * 256;
    #pragma unroll 8
    for (int l = 0; l < 256; ++l) acc = fmaf(y[l], lrow[l], acc);
    out[j * 10 + tid] = acc;
  }
}

// ---------------- launch ----------------
extern "C" void kernel_launch(void* const* d_in, const int* in_sizes, int n_in,
                              void* d_out, int out_size, void* d_ws, size_t ws_size,
                              hipStream_t stream) {
  const float* x        = (const float*)d_in[0];
  const float* drop_x   = (const float*)d_in[1];
  const float* drop_h   = (const float*)d_in[2];
  const float* drop_l   = (const float*)d_in[3];
  const float* wih_mu   = (const float*)d_in[4];
  const float* wih_rho  = (const float*)d_in[5];
  const float* eps_wih  = (const float*)d_in[6];
  const float* whh_mu   = (const float*)d_in[7];
  const float* whh_rho  = (const float*)d_in[8];
  const float* eps_whh  = (const float*)d_in[9];
  const float* b_mu     = (const float*)d_in[10];
  const float* b_rho    = (const float*)d_in[11];
  const float* eps_b    = (const float*)d_in[12];
  const float* blw_mu   = (const float*)d_in[13];
  const float* blw_rho  = (const float*)d_in[14];
  const float* eps_blw  = (const float*)d_in[15];
  const float* blb_mu   = (const float*)d_in[16];
  const float* blb_rho  = (const float*)d_in[17];
  const float* eps_blb  = (const float*)d_in[18];
  const float* lin_w    = (const float*)d_in[19];

  prep_kernel<<<513, 256, 0, stream>>>(blw_mu, blw_rho, eps_blw,
                                       blb_mu, blb_rho, eps_blb);

  lstm_kernel<<<LAUNCH_WGS, 512, 0, stream>>>(x, drop_x,
                                              wih_mu, wih_rho, eps_wih,
                                              b_mu, b_rho, eps_b,
                                              whh_mu, whh_rho, eps_whh);

  head_kernel<<<256, 256, 0, stream>>>(drop_h, drop_l, lin_w, (float*)d_out);
}

// Round 10
// 731.999 us; speedup vs baseline: 1.0730x; 1.0730x over previous
//
#include <hip/hip_runtime.h>
#include <hip/hip_fp16.h>

#define T_STEPS 336
#define NWG 32

typedef unsigned long long u64;

// Device-global scratch; sync state re-initialized by prep every call
// (device globals survive across graph replays; stale tags would break).
__device__ float g_h[337 * 512];      // h_1..h_336 (head reads t>=81)
__device__ float g_blw[256 * 512];    // sampled BayesianLinear weight
__device__ float g_blb[256];          // sampled BayesianLinear bias
__device__ u64   g_hh[2][512];        // parity buffers: (tag<<32)|h_bits

__device__ __forceinline__ float softplus_f(float x) {
  return (x > 20.f) ? x : log1pf(__expf(x));
}
__device__ __forceinline__ float sigmoid_f(float x) {
  return 1.f / (1.f + __expf(-x));
}
// Clamped tanh for the c-path (clamp prevents __expf overflow -> NaN).
__device__ __forceinline__ float tanh_f(float x) {
  x = fminf(fmaxf(x, -15.f), 15.f);
  float e = __expf(-2.f * x);
  return (1.f - e) / (1.f + e);
}

// ---------------- prep: BLW/BLb sampling + tag init ----------------
// blocks 0..511 : sample BLW -> g_blw
// block  512    : sample BLb -> g_blb; init g_hh (tag0|h0=0 both parities;
//                 parity-1 tag 0 != 1 -> no false match at t=1)
__global__ __launch_bounds__(256) void prep_kernel(
    const float* __restrict__ blw_mu, const float* __restrict__ blw_rho, const float* __restrict__ eps_blw,
    const float* __restrict__ blb_mu, const float* __restrict__ blb_rho, const float* __restrict__ eps_blb)
{
  const int bid = blockIdx.x, tid = threadIdx.x;
  if (bid < 512) {
    const int e = bid * 256 + tid;    // < 131072
    g_blw[e] = blw_mu[e] + softplus_f(blw_rho[e]) * eps_blw[e];
  } else {
    g_blb[tid] = blb_mu[tid] + softplus_f(blb_rho[tid]) * eps_blb[tid];
    u64* p = &g_hh[0][0];
    #pragma unroll
    for (int q = 0; q < 4; ++q)
      __hip_atomic_store(p + q * 256 + tid, 0ULL, __ATOMIC_RELAXED,
                         __HIP_MEMORY_SCOPE_AGENT);
  }
}

// ---------------- persistent LSTM recurrence ----------------
// 32 WGs x 512 threads (proven round-7 transport: relaxed agent/IC atomics).
// WG r owns h-indices [16r,16r+16). Thread (seg=tid>>6, cl=tid&63):
// col=(cl>>4)*512+16r+(cl&15), rows [64seg,64seg+64), 64 Whh weights in regs.
// Wave seg polls exactly the 64 h-slots its dot consumes -> no poll->dot
// barrier. part[] parity-double-buffered -> single __syncthreads per step.
// Tail: all 64 lanes activate their OWN gate value (one exp chain, parallel)
// BEFORE the shfl exchange -> 2 serial exp chains/step instead of 5.
__global__ __launch_bounds__(512) void lstm_kernel(
    const float* __restrict__ x, const float* __restrict__ drop_x,
    const float* __restrict__ wih_mu, const float* __restrict__ wih_rho, const float* __restrict__ eps_wih,
    const float* __restrict__ b_mu, const float* __restrict__ b_rho, const float* __restrict__ eps_b,
    const float* __restrict__ whh_mu, const float* __restrict__ whh_rho, const float* __restrict__ eps_whh)
{
  const int r = blockIdx.x;         // 0..31
  const int tid = threadIdx.x;      // 0..511
  const int cl = tid & 63;
  const int seg = tid >> 6;         // 0..7
  const int gate = cl >> 4, kl = cl & 15;
  const int col = gate * 512 + r * 16 + kl;
  const int row0 = seg * 64;

  __shared__ float  xd[336 * 16];   // x*drop_x for batch 255
  __shared__ __half hs16[512];      // fp16 h copy (matvec input only)
  __shared__ float  part[2][8][64]; // parity-double-buffered partials

  for (int e = tid; e < 5376; e += 512) {
    const int src = 255 * 5376 + e;   // batch-255 slice is contiguous
    xd[e] = x[src] * drop_x[src];
  }

  // 64 sampled Whh weights in registers (FULL unroll or w[] demotes to scratch).
  float w[64];
  #pragma unroll
  for (int j = 0; j < 64; ++j) {
    const int idx = (row0 + j) * 2048 + col;
    w[j] = whh_mu[idx] + softplus_f(whh_rho[idx]) * eps_whh[idx];
  }

  // Wave 0: Wih column + bias for on-the-fly xg.
  float wih[16];
  float bias = 0.f;
  if (tid < 64) {
    bias = b_mu[col] + softplus_f(b_rho[col]) * eps_b[col];
    #pragma unroll
    for (int i = 0; i < 16; ++i) {
      const int idx = i * 2048 + col;
      wih[i] = wih_mu[idx] + softplus_f(wih_rho[idx]) * eps_wih[idx];
    }
  }
  __syncthreads();                  // xd staged

  auto xg_at = [&](int t) -> float {
    const float4* xr = (const float4*)(xd + t * 16);
    float4 x0 = xr[0], x1 = xr[1], x2 = xr[2], x3 = xr[3];
    float s0 = fmaf(x0.x, wih[0], bias);
    s0 = fmaf(x0.y, wih[1], s0); s0 = fmaf(x0.z, wih[2], s0); s0 = fmaf(x0.w, wih[3], s0);
    float s1 = x1.x * wih[4];
    s1 = fmaf(x1.y, wih[5], s1); s1 = fmaf(x1.z, wih[6], s1); s1 = fmaf(x1.w, wih[7], s1);
    float s2 = x2.x * wih[8];
    s2 = fmaf(x2.y, wih[9], s2); s2 = fmaf(x2.z, wih[10], s2); s2 = fmaf(x2.w, wih[11], s2);
    float s3 = x3.x * wih[12];
    s3 = fmaf(x3.y, wih[13], s3); s3 = fmaf(x3.z, wih[14], s3); s3 = fmaf(x3.w, wih[15], s3);
    return (s0 + s1) + (s2 + s3);
  };

  float c = 0.f;                    // cell state (wave-0 lanes 0..15)
  float xgv = (tid < 64) ? xg_at(0) : 0.f;

  for (int t = 0; t < T_STEPS; ++t) {
    const int p = t & 1;

    // Poll my slot at IC (proven transport); value rides with the tag.
    {
      const u64* slot = &g_hh[p][tid];
      u64 v;
      int it = 0;
      for (;;) {
        v = __hip_atomic_load(slot, __ATOMIC_RELAXED, __HIP_MEMORY_SCOPE_AGENT);
        if ((unsigned)(v >> 32) == (unsigned)t) break;
        if (++it > (1 << 20)) break;   // anti-hang insurance (never fires in practice)
      }
      hs16[tid] = __float2half(__uint_as_float((unsigned)v));
    }
    // No barrier: wave seg's dot reads hs16[row0..row0+64) = its own lanes' data.

    float a0 = 0.f, a1 = 0.f, a2 = 0.f, a3 = 0.f;
    const float4* hv = (const float4*)(hs16 + row0);   // 8 halves per float4
    #pragma unroll
    for (int jj = 0; jj < 8; ++jj) {
      float4 q = hv[jj];
      const __half2* hp = (const __half2*)&q;
      float2 f0 = __half22float2(hp[0]);
      float2 f1 = __half22float2(hp[1]);
      float2 f2 = __half22float2(hp[2]);
      float2 f3 = __half22float2(hp[3]);
      a0 = fmaf(f0.x, w[8 * jj],     a0);
      a1 = fmaf(f0.y, w[8 * jj + 1], a1);
      a2 = fmaf(f1.x, w[8 * jj + 2], a2);
      a3 = fmaf(f1.y, w[8 * jj + 3], a3);
      a0 = fmaf(f2.x, w[8 * jj + 4], a0);
      a1 = fmaf(f2.y, w[8 * jj + 5], a1);
      a2 = fmaf(f3.x, w[8 * jj + 6], a2);
      a3 = fmaf(f3.y, w[8 * jj + 7], a3);
    }
    part[p][seg][cl] = (a0 + a1) + (a2 + a3);
    __syncthreads();   // single rendezvous per step (skew-safe via parity bufs)

    if (tid < 64) {
      float g = xgv
              + ((part[p][0][tid] + part[p][1][tid]) + (part[p][2][tid] + part[p][3][tid]))
              + ((part[p][4][tid] + part[p][5][tid]) + (part[p][6][tid] + part[p][7][tid]));
      // Activate on ALL 64 lanes in parallel (one exp chain each):
      // gates i,f,o -> sigmoid; gate g -> tanh = 2*sigmoid(2x)-1 (clamped).
      const bool is_g = (gate == 2);
      float xin = is_g ? 2.f * fminf(fmaxf(g, -15.f), 15.f) : g;
      float s = sigmoid_f(xin);
      float act = is_g ? 2.f * s - 1.f : s;
      // Exchange activated values to lanes 0..15.
      float vi = __shfl(act, kl);
      float vf = __shfl(act, kl + 16);
      float vg = __shfl(act, kl + 32);
      float vo = __shfl(act, kl + 48);
      if (tid < 16) {
        c = vf * c + vi * vg;
        float h = vo * tanh_f(c);
        const int idx = r * 16 + tid;
        u64 pv = (((u64)(unsigned)(t + 1)) << 32) | (u64)__float_as_uint(h);
        __hip_atomic_store(&g_hh[(t + 1) & 1][idx], pv,
                           __ATOMIC_RELAXED, __HIP_MEMORY_SCOPE_AGENT);
        g_h[(t + 1) * 512 + idx] = h;                      // for head (after publish)
      }
      if (t + 1 < T_STEPS) xgv = xg_at(t + 1);             // off critical path
    }
  }
}

// ---------------- head ----------------
// block j: last[j] = g_h[81+j]  (reshape(T,B,H)[-1] => h_{t=80+j} of batch 255)
// y[l] = relu(last*drop_h[j] . BLW[l] + BLb[l]) * drop_l[j,l]
// out[j,o] = sum_l y[l]*lin_w[o,l]
__global__ __launch_bounds__(256) void head_kernel(
    const float* __restrict__ drop_h, const float* __restrict__ drop_l,
    const float* __restrict__ lin_w, float* __restrict__ out)
{
  const int j = blockIdx.x, tid = threadIdx.x;
  __shared__ float hd[512];
  __shared__ float y[256];

  for (int k = tid; k < 512; k += 256)
    hd[k] = g_h[(81 + j) * 512 + k] * drop_h[j * 512 + k];
  __syncthreads();

  {
    const int l = tid;
    float acc = g_blb[l];
    const float* wrow = g_blw + l * 512;
    #pragma unroll 8
    for (int k = 0; k < 512; ++k) acc = fmaf(hd[k], wrow[k], acc);
    acc = fmaxf(acc, 0.f);
    y[l] = acc * drop_l[j * 256 + l];
  }
  __syncthreads();

  if (tid < 10) {
    float acc = 0.f;
    const float* lrow = lin_w + tid * 256;
    #pragma unroll 8
    for (int l = 0; l < 256; ++l) acc = fmaf(y[l], lrow[l], acc);
    out[j * 10 + tid] = acc;
  }
}

// ---------------- launch ----------------
extern "C" void kernel_launch(void* const* d_in, const int* in_sizes, int n_in,
                              void* d_out, int out_size, void* d_ws, size_t ws_size,
                              hipStream_t stream) {
  const float* x        = (const float*)d_in[0];
  const float* drop_x   = (const float*)d_in[1];
  const float* drop_h   = (const float*)d_in[2];
  const float* drop_l   = (const float*)d_in[3];
  const float* wih_mu   = (const float*)d_in[4];
  const float* wih_rho  = (const float*)d_in[5];
  const float* eps_wih  = (const float*)d_in[6];
  const float* whh_mu   = (const float*)d_in[7];
  const float* whh_rho  = (const float*)d_in[8];
  const float* eps_whh  = (const float*)d_in[9];
  const float* b_mu     = (const float*)d_in[10];
  const float* b_rho    = (const float*)d_in[11];
  const float* eps_b    = (const float*)d_in[12];
  const float* blw_mu   = (const float*)d_in[13];
  const float* blw_rho  = (const float*)d_in[14];
  const float* eps_blw  = (const float*)d_in[15];
  const float* blb_mu   = (const float*)d_in[16];
  const float* blb_rho  = (const float*)d_in[17];
  const float* eps_blb  = (const float*)d_in[18];
  const float* lin_w    = (const float*)d_in[19];

  prep_kernel<<<513, 256, 0, stream>>>(blw_mu, blw_rho, eps_blw,
                                       blb_mu, blb_rho, eps_blb);

  lstm_kernel<<<NWG, 512, 0, stream>>>(x, drop_x,
                                       wih_mu, wih_rho, eps_wih,
                                       b_mu, b_rho, eps_b,
                                       whh_mu, whh_rho, eps_whh);

  head_kernel<<<256, 256, 0, stream>>>(drop_h, drop_l, lin_w, (float*)d_out);
}